// Round 2
// baseline (121.812 us; speedup 1.0000x reference)
//
#include <hip/hip_runtime.h>

// SoftRAM attention: S=128, B=256 bits, H=16 heads, NB=12 bits/neuron, PB=7.
// addr(i,j,h,n) = aq_i | ak_j | ap_{i-j}, disjoint bit groups per (h,n).
//
// R10: break the 1-block/CU monolith. R8/R9 used 256 blocks x 16 waves =
// exactly 1 block/CU: every barrier drain / LDS-latency chain / fallback-wave
// tail was fully exposed (VALU 33%, HBM 10%, Occ 36% -> mostly idle).
// Now: grid 1024 = 4 head-groups x 256 neurons, 256 threads (4 waves) per
// block, ~23KB LDS -> 4 co-resident blocks/CU. One block's global-load drain
// overlaps other blocks' sweeps; barriers couple only 4 waves; fallback-heavy
// blocks no longer gate 15 other waves. Majority vote across the 4 groups
// moves to a tiny second kernel via a 128KB workspace of per-group counts
// (fully overwritten every run -> no zeroing needed).
// Per-wave math identical to R9 (verified absmax 0): register bit-LUT sweep
// for pmask==0 waves, lanes=queries scan for P-heads.

#define S 128
#define B 256
#define H 16
#define NB 12

__device__ __forceinline__ unsigned sig(unsigned x) {
    return x ^ ((x >> 3) & 0x70u) ^ ((x >> 6) & 0x70u);
}

__global__ __launch_bounds__(256, 4) void softram_kernel(
    const int* __restrict__ tokens,        // [S,B] 0/1
    const float* __restrict__ memory,      // [H,B,4096]
    const int* __restrict__ connections,   // [H,B,NB]
    unsigned char* __restrict__ pc)        // [4][256][128] per-group counts
{
    const int bid  = blockIdx.x;
    const int g    = bid >> 8;             // head group (0..3)
    const int n    = bid & 255;            // neuron
    const int tid  = threadIdx.x;
    const int wid  = tid >> 6;             // wave in block (0..3)
    const int hg   = g * 4 + wid;          // global head
    const int lane = tid & 63;

    __shared__ unsigned char  bytetab[4 * 4096];   // 16 KB sigma-packed signs
    __shared__ unsigned int   tokT[8][S];          // 4 KB transposed token bits
    __shared__ unsigned short akT[4][S];           // key class (fast) / sig(ak) (fb)
    __shared__ unsigned short apt[4][S];           // sig(ap) by dist (fallback only)
    __shared__ int            conns[4][NB];        // 192 B
    __shared__ unsigned int   parts[4][4];         // 128 result bits per head

    // ---- issue own head's 16KB row load first (drains by barrier #1) ----
    const float4* mrow = (const float4*)(memory + ((size_t)(hg * 256 + n) << 12));
    float4 va[16];
    #pragma unroll
    for (int t = 0; t < 16; ++t) va[t] = mrow[lane + 64 * t];

    // ---- token pack (transposed: tokT[w][i]); 4 words per thread ----
    {
        int i = tid >> 1, half = tid & 1;
        const int4* tp = (const int4*)tokens;
        #pragma unroll
        for (int wl = 0; wl < 4; ++wl) {
            int w = half * 4 + wl;
            unsigned v = 0;
            #pragma unroll
            for (int u = 0; u < 8; ++u) {
                int4 x = tp[i * 64 + w * 8 + u];
                v |= (unsigned)(x.x & 1) << (4 * u + 0);
                v |= (unsigned)(x.y & 1) << (4 * u + 1);
                v |= (unsigned)(x.z & 1) << (4 * u + 2);
                v |= (unsigned)(x.w & 1) << (4 * u + 3);
            }
            tokT[w][i] = v;
        }
    }
    if (tid < 4 * NB) {
        int hh = tid / NB, b = tid - hh * NB;
        conns[hh][b] = connections[(size_t)(g * 4 + hh) * (B * NB) + n * NB + b];
    }
    __syncthreads();   // barrier #1: tokT + conns visible (va also drained)

    // ---- per-head masks (wave-uniform) ----
    unsigned qmask = 0, kmask = 0, pmask = 0;
    #pragma unroll
    for (int b = 0; b < NB; ++b) {
        int c = conns[wid][b];
        qmask |= (unsigned)(c < 256) << b;
        kmask |= (unsigned)(c >= 256 && c < 512) << b;
        pmask |= (unsigned)(c >= 512) << b;
    }
    const int qb = __popc(qmask);
    const int kb = __popc(kmask);

    unsigned char* __restrict__ bt = &bytetab[wid << 12];
    unsigned long long rlo = 0, rhi = 0;

    if (pmask == 0) {
        // ================= fast path: register bit-LUT =================
        unsigned qcls0 = 0, qcls1 = 0;
        #pragma unroll
        for (int e = 0; e < 2; ++e) {
            int ii = lane + 64 * e;
            unsigned qc = 0, kc = 0;
            int qn = 0, kn = 0;
            #pragma unroll
            for (int b = 0; b < NB; ++b) {
                int c = conns[wid][b];     // wave-uniform -> uniform branches
                if (c < 256) {
                    qc |= ((tokT[c >> 5][ii] >> (c & 31)) & 1u) << qn;
                    ++qn;
                } else {
                    int c2 = c - 256;
                    kc |= ((tokT[c2 >> 5][ii] >> (c2 & 31)) & 1u) << kn;
                    ++kn;
                }
            }
            akT[wid][ii] = (unsigned short)kc;
            if (e == 0) qcls0 = qc; else qcls1 = qc;
        }

        // sign pack into sigma-addressed bytes (staging for the repack)
        #pragma unroll
        for (int t = 0; t < 16; ++t) {
            float4 v = va[t];
            unsigned p = 4u * (unsigned)(lane + 64 * t);
            unsigned w = (unsigned)(v.x > 0.f)
                       | ((unsigned)(v.y > 0.f) << 8)
                       | ((unsigned)(v.z > 0.f) << 16)
                       | ((unsigned)(v.w > 0.f) << 24);
            *(unsigned*)&bt[sig(p)] = w;   // sigma keeps bits 0-3 -> aligned dword
        }

        // ---- repack to lane-distributed bit-LUT: lane w holds global bits
        //      g in [64w, 64w+64), gbit = (Lcls << SBITS) | Scls. ----
        const bool formA = (qb <= 6);          // bit-side = Q if qb<=6 else K
        const int SBITS  = formA ? qb : kb;
        unsigned apl = 0, aul = 0;             // per-lane / per-iter addr parts
        {
            int scnt = 0, lcnt = 0;
            #pragma unroll
            for (int b = 0; b < NB; ++b) {
                int c = conns[wid][b];
                bool isS = formA ? (c < 256) : (c >= 256);
                if (isS) {                     // g-bit scnt (< 6) -> lane bit
                    apl |= (((unsigned)lane >> scnt) & 1u) << b;
                    ++scnt;
                } else {
                    int p = SBITS + lcnt;      // g-bit position of this L bit
                    if (p < 6) apl |= (((unsigned)lane >> p) & 1u) << b;
                    else       aul |= (((unsigned)lane >> (p - 6)) & 1u) << b;
                    ++lcnt;
                }
            }
        }
        const unsigned spl  = sig(apl);
        const unsigned saul = sig(aul);        // lane x holds sig(addr) part for it=x
        unsigned Wlo = 0, Whi = 0;
        #pragma unroll 8
        for (int it = 0; it < 64; ++it) {
            unsigned sau  = (unsigned)__builtin_amdgcn_readlane((int)saul, it);
            unsigned bitv = bt[sau ^ spl] & 1u;          // sign at gbit = it*64+lane
            unsigned long long Bm = __ballot(bitv != 0u);
            Wlo = (lane == it) ? (unsigned)Bm : Wlo;
            Whi = (lane == it) ? (unsigned)(Bm >> 32) : Whi;
        }

        if (formA) {
            // scan keys; A = xor of LUT words of keys seen so far; capture at
            // the causal diagonal. r_i = bit qcls_i of capture.
            unsigned long long A = 0, cap0 = 0, cap1 = 0;
            for (int s8 = 0; s8 < 8; ++s8) {
                uint4 uk = *(const uint4*)&akT[wid][s8 * 8];
                #pragma unroll
                for (int t = 0; t < 8; ++t) {
                    int j = s8 * 8 + t;
                    unsigned w = ((const unsigned*)&uk)[t >> 1];
                    unsigned widx = (unsigned)__builtin_amdgcn_readfirstlane(
                        (int)((w >> ((t & 1) * 16)) & 0xffffu));
                    unsigned g0 = widx << qb;
                    int lsel = (int)(g0 >> 6);
                    unsigned lo = (unsigned)__builtin_amdgcn_readlane((int)Wlo, lsel);
                    unsigned hi = (unsigned)__builtin_amdgcn_readlane((int)Whi, lsel);
                    A ^= ((((unsigned long long)hi << 32) | lo) >> (g0 & 63u));
                    cap0 = (lane == j) ? A : cap0;
                }
            }
            for (int s8 = 8; s8 < 16; ++s8) {
                uint4 uk = *(const uint4*)&akT[wid][s8 * 8];
                #pragma unroll
                for (int t = 0; t < 8; ++t) {
                    int j = s8 * 8 + t;
                    unsigned w = ((const unsigned*)&uk)[t >> 1];
                    unsigned widx = (unsigned)__builtin_amdgcn_readfirstlane(
                        (int)((w >> ((t & 1) * 16)) & 0xffffu));
                    unsigned g0 = widx << qb;
                    int lsel = (int)(g0 >> 6);
                    unsigned lo = (unsigned)__builtin_amdgcn_readlane((int)Wlo, lsel);
                    unsigned hi = (unsigned)__builtin_amdgcn_readlane((int)Whi, lsel);
                    A ^= ((((unsigned long long)hi << 32) | lo) >> (g0 & 63u));
                    cap1 = (lane == j - 64) ? A : cap1;
                }
            }
            rlo = __ballot(((cap0 >> qcls0) & 1ull) != 0ull);
            rhi = __ballot(((cap1 >> qcls1) & 1ull) != 0ull);
        } else {
            // kb <= 5: C = xor of one-hot key classes (prefix parity word);
            // r_i = parity(LUTrow[qcls_i] & C_i).
            unsigned Cw = 0, cap0 = 0, cap1 = 0;
            for (int s8 = 0; s8 < 8; ++s8) {
                uint4 uk = *(const uint4*)&akT[wid][s8 * 8];
                #pragma unroll
                for (int t = 0; t < 8; ++t) {
                    int j = s8 * 8 + t;
                    unsigned w = ((const unsigned*)&uk)[t >> 1];
                    unsigned widx = (unsigned)__builtin_amdgcn_readfirstlane(
                        (int)((w >> ((t & 1) * 16)) & 0xffffu));
                    Cw ^= 1u << widx;
                    cap0 = (lane == j) ? Cw : cap0;
                }
            }
            for (int s8 = 8; s8 < 16; ++s8) {
                uint4 uk = *(const uint4*)&akT[wid][s8 * 8];
                #pragma unroll
                for (int t = 0; t < 8; ++t) {
                    int j = s8 * 8 + t;
                    unsigned w = ((const unsigned*)&uk)[t >> 1];
                    unsigned widx = (unsigned)__builtin_amdgcn_readfirstlane(
                        (int)((w >> ((t & 1) * 16)) & 0xffffu));
                    Cw ^= 1u << widx;
                    cap1 = (lane == j - 64) ? Cw : cap1;
                }
            }
            unsigned g0a = qcls0 << kb, g0b = qcls1 << kb;
            unsigned lo0 = (unsigned)__shfl((int)Wlo, (int)(g0a >> 6));
            unsigned hi0 = (unsigned)__shfl((int)Whi, (int)(g0a >> 6));
            unsigned lo1 = (unsigned)__shfl((int)Wlo, (int)(g0b >> 6));
            unsigned hi1 = (unsigned)__shfl((int)Whi, (int)(g0b >> 6));
            unsigned W0 = (unsigned)((((unsigned long long)hi0 << 32) | lo0) >> (g0a & 63u));
            unsigned W1 = (unsigned)((((unsigned long long)hi1 << 32) | lo1) >> (g0b & 63u));
            rlo = __ballot((__popc(W0 & cap0) & 1) != 0);
            rhi = __ballot((__popc(W1 & cap1) & 1) != 0);
        }
    } else {
        // ================= P fallback: lanes = queries =================
        unsigned aqv0 = 0, aqv1 = 0;
        #pragma unroll
        for (int e = 0; e < 2; ++e) {
            int ii = lane + 64 * e;
            unsigned aq = 0, ak = 0, ap = 0;
            #pragma unroll
            for (int b = 0; b < NB; ++b) {
                int c = conns[wid][b];
                if (c < 256) {
                    aq |= ((tokT[c >> 5][ii] >> (c & 31)) & 1u) << b;
                } else if (c < 512) {
                    int c2 = c - 256;
                    ak |= ((tokT[c2 >> 5][ii] >> (c2 & 31)) & 1u) << b;
                } else {
                    ap |= (((unsigned)ii >> (c - 512)) & 1u) << b;
                }
            }
            akT[wid][ii] = (unsigned short)sig(ak);
            apt[wid][ii] = (unsigned short)sig(ap);
            if (e == 0) aqv0 = sig(aq); else aqv1 = sig(aq);
        }

        #pragma unroll
        for (int t = 0; t < 16; ++t) {
            float4 v = va[t];
            unsigned p = 4u * (unsigned)(lane + 64 * t);
            unsigned w = (unsigned)(v.x > 0.f)
                       | ((unsigned)(v.y > 0.f) << 8)
                       | ((unsigned)(v.z > 0.f) << 16)
                       | ((unsigned)(v.w > 0.f) << 24);
            *(unsigned*)&bt[sig(p)] = w;
        }

        // queries i=lane (acc0) and i=lane+64 (acc1); arithmetic causal masks.
        unsigned acc0 = 0, acc1 = 0;
        for (int s8 = 0; s8 < 8; ++s8) {       // j = 0..63
            uint4 uk = *(const uint4*)&akT[wid][s8 * 8];
            #pragma unroll
            for (int t = 0; t < 8; ++t) {
                int j = s8 * 8 + t;
                unsigned w = ((const unsigned*)&uk)[t >> 1];
                unsigned akv = (w >> ((t & 1) * 16)) & 0xffffu;
                int d0 = lane - j;             // <0 -> masked out
                unsigned v0 = bt[aqv0 ^ akv ^ (unsigned)apt[wid][d0 & 127]] & 1u;
                acc0 ^= (d0 >= 0) ? v0 : 0u;
                int d1 = lane + 64 - j;        // in [1,127]: always active
                unsigned v1 = bt[aqv1 ^ akv ^ (unsigned)apt[wid][d1]] & 1u;
                acc1 ^= v1;
            }
        }
        for (int s8 = 8; s8 < 16; ++s8) {      // j = 64..127: only upper query
            uint4 uk = *(const uint4*)&akT[wid][s8 * 8];
            #pragma unroll
            for (int t = 0; t < 8; ++t) {
                int j = s8 * 8 + t;
                unsigned w = ((const unsigned*)&uk)[t >> 1];
                unsigned akv = (w >> ((t & 1) * 16)) & 0xffffu;
                int d1 = lane + 64 - j;        // <0 -> masked out
                unsigned v1 = bt[aqv1 ^ akv ^ (unsigned)apt[wid][d1 & 127]] & 1u;
                acc1 ^= (d1 >= 0) ? v1 : 0u;
            }
        }
        rlo = __ballot(acc0 != 0u);
        rhi = __ballot(acc1 != 0u);
    }

    if (lane == 0) {
        parts[wid][0] = (unsigned)rlo;
        parts[wid][1] = (unsigned)(rlo >> 32);
        parts[wid][2] = (unsigned)rhi;
        parts[wid][3] = (unsigned)(rhi >> 32);
    }
    __syncthreads();   // barrier #2: parts visible

    // ---- per-group count (0..4) per query bit; fully overwrites slot ----
    if (tid < S) {
        int i = tid, tot = 0;
        #pragma unroll
        for (int hh = 0; hh < 4; ++hh)
            tot += (parts[hh][i >> 5] >> (i & 31)) & 1;
        pc[((size_t)g * 256 + n) * 128 + i] = (unsigned char)tot;
    }
}

__global__ __launch_bounds__(128) void vote_kernel(
    const unsigned char* __restrict__ pc,  // [4][256][128]
    int* __restrict__ out)                 // [S,B]
{
    const int n = blockIdx.x;              // 0..255
    const int i = threadIdx.x;             // 0..127
    int tot = pc[(size_t)(0 * 256 + n) * 128 + i]
            + pc[(size_t)(1 * 256 + n) * 128 + i]
            + pc[(size_t)(2 * 256 + n) * 128 + i]
            + pc[(size_t)(3 * 256 + n) * 128 + i];
    out[i * B + n] = (tot > (H / 2)) ? 1 : 0;
}

extern "C" void kernel_launch(void* const* d_in, const int* in_sizes, int n_in,
                              void* d_out, int out_size, void* d_ws, size_t ws_size,
                              hipStream_t stream) {
    const int*   tokens      = (const int*)d_in[0];
    const float* memory      = (const float*)d_in[1];
    const int*   connections = (const int*)d_in[2];
    int*         out         = (int*)d_out;
    unsigned char* pc        = (unsigned char*)d_ws;   // 4*256*128 = 128 KB
    (void)in_sizes; (void)n_in; (void)out_size; (void)ws_size;

    softram_kernel<<<4 * B, 256, 0, stream>>>(tokens, memory, connections, pc);
    vote_kernel<<<B, 128, 0, stream>>>(pc, out);
}

// Round 3
// 109.954 us; speedup vs baseline: 1.1078x; 1.1078x over previous
//
#include <hip/hip_runtime.h>

// SoftRAM attention: S=128, B=256 bits, H=16 heads, NB=12 bits/neuron, PB=7.
// addr(i,j,h,n) = aq_i | ak_j | ap_{i-j}, disjoint bit groups per (h,n).
//
// R11: kill the two things R10's counters exposed (35% VALUBusy flat under a
// TLP change => concurrent per-CU stall + high per-wave instr count):
//  1. Token pack hoisted to a one-shot pack_kernel (8 blocks, coalesced row
//     loads + 4 ballots/row -> 4KB packed table in workspace). Main kernel
//     loads 4KB coalesced instead of every block re-gathering the whole
//     128KB tokens array with 64-line scattered wave-loads (was ~128MB of
//     L2 request traffic + ~700 VALU/wave, all pre-barrier, every CU).
//     Packed layout: token bit c -> word ((c&3)<<1)+(c>>7), pos (c>>2)&31.
//  2. Fast-path sweeps de-scalarized: the uniform 128-iter A-chain (~1000
//     issue slots of readfirstlane/readlane/xor/cndmask) becomes a
//     lane-parallel inclusive prefix-XOR: per-lane LUT gather via __shfl +
//     6-step __shfl_up butterfly + ballot (~90 instr). Same math.
//  3. Repack capture via v_writelane instead of cmp+2 cndmask.
// Per-wave math otherwise identical to R9/R10 (both verified absmax 0).

#define S 128
#define B 256
#define H 16
#define NB 12

__device__ __forceinline__ unsigned sig(unsigned x) {
    return x ^ ((x >> 3) & 0x70u) ^ ((x >> 6) & 0x70u);
}

// token bit c lives at packed word TW(c), bit TP(c)
#define TW(c) ((((c) & 3) << 1) + ((c) >> 7))
#define TP(c) (((c) >> 2) & 31)

__global__ __launch_bounds__(256) void pack_kernel(
    const int* __restrict__ tokens,        // [S,B] 0/1
    unsigned* __restrict__ tokP)           // [8][S] packed
{
    const int wid  = threadIdx.x >> 6;
    const int lane = threadIdx.x & 63;
    const int4* tp = (const int4*)tokens;
    #pragma unroll
    for (int r = 0; r < 4; ++r) {
        int i = blockIdx.x * 16 + wid * 4 + r;
        int4 x = tp[i * 64 + lane];        // coalesced: full row of 256 ints
        unsigned long long B0 = __ballot((x.x & 1) != 0);  // bit l = tok[4l+0]
        unsigned long long B1 = __ballot((x.y & 1) != 0);
        unsigned long long B2 = __ballot((x.z & 1) != 0);
        unsigned long long B3 = __ballot((x.w & 1) != 0);
        int c = lane >> 1;                 // word index = comp*2 + half
        unsigned long long s01 = (c & 1) ? B1 : B0;
        unsigned long long s23 = (c & 1) ? B3 : B2;
        unsigned long long s   = (c & 2) ? s23 : s01;
        unsigned word = (lane & 1) ? (unsigned)(s >> 32) : (unsigned)s;
        if (lane < 8) tokP[lane * 128 + i] = word;
    }
}

__global__ __launch_bounds__(256, 4) void softram_kernel(
    const unsigned* __restrict__ tokP,     // [8][S] packed tokens
    const float* __restrict__ memory,      // [H,B,4096]
    const int* __restrict__ connections,   // [H,B,NB]
    unsigned char* __restrict__ pc)        // [4][256][128] per-group counts
{
    const int bid  = blockIdx.x;
    const int g    = bid >> 8;             // head group (0..3)
    const int n    = bid & 255;            // neuron
    const int tid  = threadIdx.x;
    const int wid  = tid >> 6;             // wave in block (0..3)
    const int hg   = g * 4 + wid;          // global head
    const int lane = tid & 63;

    __shared__ __align__(16) unsigned char  bytetab[4 * 4096];  // 16 KB signs
    __shared__ __align__(16) unsigned int   tokT[8 * S];        // 4 KB packed
    __shared__ __align__(16) unsigned short akT[4][S];          // key class / sig(ak)
    __shared__ __align__(16) unsigned short apt[4][S];          // sig(ap) (fallback)
    __shared__ int            conns[4][NB];
    __shared__ unsigned int   parts[4][4];

    // ---- issue own head's 16KB row load first ----
    const float4* mrow = (const float4*)(memory + ((size_t)(hg * 256 + n) << 12));
    float4 va[16];
    #pragma unroll
    for (int t = 0; t < 16; ++t) va[t] = mrow[lane + 64 * t];

    // ---- stage packed tokens (4KB, coalesced, L2-hot) + conns ----
    ((int4*)tokT)[tid] = ((const int4*)tokP)[tid];
    if (tid < 4 * NB) {
        int hh = tid / NB, b = tid - hh * NB;
        conns[hh][b] = connections[(size_t)(g * 4 + hh) * (B * NB) + n * NB + b];
    }
    __syncthreads();   // barrier #1

    // ---- per-head masks (wave-uniform) ----
    unsigned qmask = 0, kmask = 0, pmask = 0;
    #pragma unroll
    for (int b = 0; b < NB; ++b) {
        int c = conns[wid][b];
        qmask |= (unsigned)(c < 256) << b;
        kmask |= (unsigned)(c >= 256 && c < 512) << b;
        pmask |= (unsigned)(c >= 512) << b;
    }
    const int qb = __popc(qmask);
    const int kb = __popc(kmask);

    unsigned char* __restrict__ bt = &bytetab[wid << 12];
    unsigned long long rlo = 0, rhi = 0;

    if (pmask == 0) {
        // ================= fast path: register bit-LUT =================
        unsigned qclsA = 0, qclsB = 0;     // query class for i=lane, i=lane+64
        #pragma unroll
        for (int e = 0; e < 2; ++e) {
            int ii = lane + 64 * e;
            unsigned qc = 0, kc = 0;
            int qn = 0, kn = 0;
            #pragma unroll
            for (int b = 0; b < NB; ++b) {
                int c = conns[wid][b];     // wave-uniform -> uniform branches
                if (c < 256) {
                    qc |= ((tokT[TW(c) * S + ii] >> TP(c)) & 1u) << qn;
                    ++qn;
                } else {
                    int c2 = c - 256;
                    kc |= ((tokT[TW(c2) * S + ii] >> TP(c2)) & 1u) << kn;
                    ++kn;
                }
            }
            akT[wid][ii] = (unsigned short)kc;
            if (e == 0) qclsA = qc; else qclsB = qc;
        }

        // sign pack into sigma-addressed bytes (staging for the repack)
        #pragma unroll
        for (int t = 0; t < 16; ++t) {
            float4 v = va[t];
            unsigned p = 4u * (unsigned)(lane + 64 * t);
            unsigned w = (unsigned)(v.x > 0.f)
                       | ((unsigned)(v.y > 0.f) << 8)
                       | ((unsigned)(v.z > 0.f) << 16)
                       | ((unsigned)(v.w > 0.f) << 24);
            *(unsigned*)&bt[sig(p)] = w;   // sigma keeps bits 0-3 -> aligned dword
        }

        // ---- repack to lane-distributed bit-LUT: lane w holds global bits
        //      gbit in [64w, 64w+64), gbit = (Lcls << SBITS) | Scls. ----
        const bool formA = (qb <= 6);      // bit-side = Q if qb<=6 else K
        const int SBITS  = formA ? qb : kb;
        unsigned apl = 0, aul = 0;
        {
            int scnt = 0, lcnt = 0;
            #pragma unroll
            for (int b = 0; b < NB; ++b) {
                int c = conns[wid][b];
                bool isS = formA ? (c < 256) : (c >= 256);
                if (isS) {
                    apl |= (((unsigned)lane >> scnt) & 1u) << b;
                    ++scnt;
                } else {
                    int p = SBITS + lcnt;
                    if (p < 6) apl |= (((unsigned)lane >> p) & 1u) << b;
                    else       aul |= (((unsigned)lane >> (p - 6)) & 1u) << b;
                    ++lcnt;
                }
            }
        }
        const unsigned spl  = sig(apl);
        const unsigned saul = sig(aul);
        unsigned Wlo = 0, Whi = 0;
        #pragma unroll 8
        for (int it = 0; it < 64; ++it) {
            unsigned sau  = (unsigned)__builtin_amdgcn_readlane((int)saul, it);
            unsigned bitv = bt[sau ^ spl] & 1u;   // sign at gbit = it*64+lane
            unsigned long long Bm = __ballot(bitv != 0u);
#if __has_builtin(__builtin_amdgcn_writelane)
            Wlo = (unsigned)__builtin_amdgcn_writelane((int)(unsigned)Bm, it, (int)Wlo);
            Whi = (unsigned)__builtin_amdgcn_writelane((int)(unsigned)(Bm >> 32), it, (int)Whi);
#else
            Wlo = (lane == it) ? (unsigned)Bm : Wlo;
            Whi = (lane == it) ? (unsigned)(Bm >> 32) : Whi;
#endif
        }
        const unsigned long long Wfull = ((unsigned long long)Whi << 32) | Wlo;

        if (formA) {
            // lane-parallel prefix-XOR over keys. lane j = key j (half 1),
            // key 64+j (half 2). V_j = LUTword(kcls_j) >> (g0_j & 63);
            // prefix_j = XOR_{j'<=j} V_j'; r_i (i=j) = bit qcls_i of prefix_j.
            unsigned kclsA = akT[wid][lane];
            unsigned g0 = kclsA << qb;
            unsigned long long V = __shfl(Wfull, (int)(g0 >> 6)) >> (g0 & 63u);
            #pragma unroll
            for (int d = 1; d < 64; d <<= 1) {
                unsigned long long u = __shfl_up(V, (unsigned)d);
                V ^= (lane >= d) ? u : 0ull;
            }
            rlo = __ballot(((V >> qclsA) & 1ull) != 0ull);
            const unsigned long long Abase = __shfl(V, 63);

            unsigned kclsB = akT[wid][64 + lane];
            unsigned g1 = kclsB << qb;
            unsigned long long V1 = __shfl(Wfull, (int)(g1 >> 6)) >> (g1 & 63u);
            #pragma unroll
            for (int d = 1; d < 64; d <<= 1) {
                unsigned long long u = __shfl_up(V1, (unsigned)d);
                V1 ^= (lane >= d) ? u : 0ull;
            }
            V1 ^= Abase;
            rhi = __ballot(((V1 >> qclsB) & 1ull) != 0ull);
        } else {
            // kb <= 5: prefix-XOR of one-hot key classes (32-bit), then
            // r_i = parity(LUTrow[qcls_i] & prefix_i).
            unsigned kclsA = akT[wid][lane];
            unsigned C = 1u << kclsA;
            #pragma unroll
            for (int d = 1; d < 64; d <<= 1) {
                unsigned u = __shfl_up(C, (unsigned)d);
                C ^= (lane >= d) ? u : 0u;
            }
            unsigned g0a = qclsA << kb;
            unsigned W0 = (unsigned)(__shfl(Wfull, (int)(g0a >> 6)) >> (g0a & 63u));
            rlo = __ballot((__popc(W0 & C) & 1) != 0);
            const unsigned Cbase = __shfl(C, 63);

            unsigned kclsB = akT[wid][64 + lane];
            unsigned C1 = 1u << kclsB;
            #pragma unroll
            for (int d = 1; d < 64; d <<= 1) {
                unsigned u = __shfl_up(C1, (unsigned)d);
                C1 ^= (lane >= d) ? u : 0u;
            }
            C1 ^= Cbase;
            unsigned g0b = qclsB << kb;
            unsigned W1 = (unsigned)(__shfl(Wfull, (int)(g0b >> 6)) >> (g0b & 63u));
            rhi = __ballot((__popc(W1 & C1) & 1) != 0);
        }
    } else {
        // ================= P fallback: lanes = queries =================
        unsigned aqv0 = 0, aqv1 = 0;
        #pragma unroll
        for (int e = 0; e < 2; ++e) {
            int ii = lane + 64 * e;
            unsigned aq = 0, ak = 0, ap = 0;
            #pragma unroll
            for (int b = 0; b < NB; ++b) {
                int c = conns[wid][b];
                if (c < 256) {
                    aq |= ((tokT[TW(c) * S + ii] >> TP(c)) & 1u) << b;
                } else if (c < 512) {
                    int c2 = c - 256;
                    ak |= ((tokT[TW(c2) * S + ii] >> TP(c2)) & 1u) << b;
                } else {
                    ap |= (((unsigned)ii >> (c - 512)) & 1u) << b;
                }
            }
            akT[wid][ii] = (unsigned short)sig(ak);
            apt[wid][ii] = (unsigned short)sig(ap);
            if (e == 0) aqv0 = sig(aq); else aqv1 = sig(aq);
        }

        #pragma unroll
        for (int t = 0; t < 16; ++t) {
            float4 v = va[t];
            unsigned p = 4u * (unsigned)(lane + 64 * t);
            unsigned w = (unsigned)(v.x > 0.f)
                       | ((unsigned)(v.y > 0.f) << 8)
                       | ((unsigned)(v.z > 0.f) << 16)
                       | ((unsigned)(v.w > 0.f) << 24);
            *(unsigned*)&bt[sig(p)] = w;
        }

        // queries i=lane (acc0) and i=lane+64 (acc1); arithmetic causal masks.
        unsigned acc0 = 0, acc1 = 0;
        for (int s8 = 0; s8 < 8; ++s8) {       // j = 0..63
            uint4 uk = *(const uint4*)&akT[wid][s8 * 8];
            #pragma unroll
            for (int t = 0; t < 8; ++t) {
                int j = s8 * 8 + t;
                unsigned w = ((const unsigned*)&uk)[t >> 1];
                unsigned akv = (w >> ((t & 1) * 16)) & 0xffffu;
                int d0 = lane - j;             // <0 -> masked out
                unsigned v0 = bt[aqv0 ^ akv ^ (unsigned)apt[wid][d0 & 127]] & 1u;
                acc0 ^= (d0 >= 0) ? v0 : 0u;
                int d1 = lane + 64 - j;        // in [1,127]: always active
                unsigned v1 = bt[aqv1 ^ akv ^ (unsigned)apt[wid][d1]] & 1u;
                acc1 ^= v1;
            }
        }
        for (int s8 = 8; s8 < 16; ++s8) {      // j = 64..127: only upper query
            uint4 uk = *(const uint4*)&akT[wid][s8 * 8];
            #pragma unroll
            for (int t = 0; t < 8; ++t) {
                int j = s8 * 8 + t;
                unsigned w = ((const unsigned*)&uk)[t >> 1];
                unsigned akv = (w >> ((t & 1) * 16)) & 0xffffu;
                int d1 = lane + 64 - j;        // <0 -> masked out
                unsigned v1 = bt[aqv1 ^ akv ^ (unsigned)apt[wid][d1 & 127]] & 1u;
                acc1 ^= (d1 >= 0) ? v1 : 0u;
            }
        }
        rlo = __ballot(acc0 != 0u);
        rhi = __ballot(acc1 != 0u);
    }

    if (lane == 0) {
        parts[wid][0] = (unsigned)rlo;
        parts[wid][1] = (unsigned)(rlo >> 32);
        parts[wid][2] = (unsigned)rhi;
        parts[wid][3] = (unsigned)(rhi >> 32);
    }
    __syncthreads();   // barrier #2: parts visible

    // ---- per-group count (0..4) per query bit; fully overwrites slot ----
    if (tid < S) {
        int i = tid, tot = 0;
        #pragma unroll
        for (int hh = 0; hh < 4; ++hh)
            tot += (parts[hh][i >> 5] >> (i & 31)) & 1;
        pc[((size_t)g * 256 + n) * 128 + i] = (unsigned char)tot;
    }
}

__global__ __launch_bounds__(128) void vote_kernel(
    const unsigned char* __restrict__ pc,  // [4][256][128]
    int* __restrict__ out)                 // [S,B]
{
    const int n = blockIdx.x;              // 0..255
    const int i = threadIdx.x;             // 0..127
    int tot = pc[(size_t)(0 * 256 + n) * 128 + i]
            + pc[(size_t)(1 * 256 + n) * 128 + i]
            + pc[(size_t)(2 * 256 + n) * 128 + i]
            + pc[(size_t)(3 * 256 + n) * 128 + i];
    out[i * B + n] = (tot > (H / 2)) ? 1 : 0;
}

extern "C" void kernel_launch(void* const* d_in, const int* in_sizes, int n_in,
                              void* d_out, int out_size, void* d_ws, size_t ws_size,
                              hipStream_t stream) {
    const int*   tokens      = (const int*)d_in[0];
    const float* memory      = (const float*)d_in[1];
    const int*   connections = (const int*)d_in[2];
    int*         out         = (int*)d_out;
    unsigned char* pc        = (unsigned char*)d_ws;              // 128 KB
    unsigned*      tokP      = (unsigned*)((char*)d_ws + 4 * 256 * 128);  // 4 KB
    (void)in_sizes; (void)n_in; (void)out_size; (void)ws_size;

    pack_kernel<<<8, 256, 0, stream>>>(tokens, tokP);
    softram_kernel<<<4 * B, 256, 0, stream>>>(tokP, memory, connections, pc);
    vote_kernel<<<B, 128, 0, stream>>>(pc, out);
}